// Round 7
// baseline (290.940 us; speedup 1.0000x reference)
//
#include <hip/hip_runtime.h>
#include <math.h>

#define N_CELLS 2048
#define D_IN 512
#define D_HID 1024
#define D_OUT 512

typedef __attribute__((ext_vector_type(8))) short bf16x8;
typedef __attribute__((ext_vector_type(4))) float f32x4;
typedef __attribute__((ext_vector_type(4))) short short4v;

#define MFMA16(a, b, c) __builtin_amdgcn_mfma_f32_16x16x32_bf16(a, b, c, 0, 0, 0)

__device__ __forceinline__ short f2bf(float f) {
  union { float f; unsigned u; } v; v.f = f;
  unsigned r = (v.u + 0x7FFFu + ((v.u >> 16) & 1u)) >> 16;
  return (short)r;
}

__device__ __forceinline__ float bf2f(unsigned short u) {
  union { unsigned u; float f; } v; v.u = ((unsigned)u) << 16; return v.f;
}

__device__ __forceinline__ void gl_lds16(const void* g, void* l) {
  __builtin_amdgcn_global_load_lds(
      (const __attribute__((address_space(1))) void*)g,
      (__attribute__((address_space(3))) void*)l, 16, 0, 0);
}

// ---------------- prep: ALL independent prep work in ONE launch ----------------
// z 0..3 : gate weight transposes (x < 1536 -> xx=k-tile, yy=n-tile)
// z == 4 : wd transpose (xx<32, yy<16)
// z == 5 : h fp32->bf16 + |h| into gatesA cols 512.. ; zero tens (x < 2048)
// z == 6 : x<16 bias partials ; 16<=x<32 zero fs accumulators
__global__ __launch_bounds__(256) void k_prep_all(
    const float* __restrict__ w0, const float* __restrict__ w1,
    const float* __restrict__ w2, const float* __restrict__ w3,
    short* __restrict__ t0, short* __restrict__ t1,
    short* __restrict__ t2, short* __restrict__ t3,
    const float* __restrict__ ea_wr, const float* __restrict__ eg_wr,
    const float* __restrict__ ea_wi, const float* __restrict__ eg_wi,
    short* __restrict__ wdrT, short* __restrict__ wdiT, short* __restrict__ wdnT,
    const float* __restrict__ h_re, const float* __restrict__ h_im,
    short* __restrict__ hbre, short* __restrict__ hbim, short* __restrict__ gatesA,
    float* __restrict__ tens,
    const float* __restrict__ x,
    float* __restrict__ bpartr, float* __restrict__ bparti,
    float* __restrict__ fsbuf) {
  __shared__ float ts0[32][33], ts1[32][33];
  const int z = blockIdx.z;
  const int bx = blockIdx.x;
  const int tid = threadIdx.x;
  if (z < 4) {
    if (bx >= 1536) return;
    const int xx = bx % 48, yy = bx / 48;
    const float* w = (z == 0) ? w0 : (z == 1) ? w1 : (z == 2) ? w2 : w3;
    short* wT = (z == 0) ? t0 : (z == 1) ? t1 : (z == 2) ? t2 : t3;
    const int k0 = xx * 32, n0 = yy * 32;
    const int c = tid & 31, r4 = tid >> 5;
#pragma unroll
    for (int i = 0; i < 4; ++i) {
      int kl = r4 * 4 + i;
      int k = k0 + kl;
      int srcrow = (k < 512) ? k : k + 1;
      ts0[kl][c] = w[(size_t)srcrow * D_HID + n0 + c];
    }
    __syncthreads();
#pragma unroll
    for (int i = 0; i < 4; ++i) {
      int nl = r4 * 4 + i;
      wT[(size_t)(n0 + nl) * 1536 + k0 + c] = f2bf(ts0[c][nl]);
    }
  } else if (z == 4) {
    const int xx = bx % 48, yy = bx / 48;
    if (xx >= 32 || yy >= 16) return;
    const int k0 = xx * 32, n0 = yy * 32;
    const int c = tid & 31, r4 = tid >> 5;
#pragma unroll
    for (int i = 0; i < 4; ++i) {
      int kl = r4 * 4 + i;
      int src = (512 + k0 + kl) * D_OUT + n0 + c;
      ts0[kl][c] = ea_wr[src] - eg_wr[src];
      ts1[kl][c] = ea_wi[src] - eg_wi[src];
    }
    __syncthreads();
#pragma unroll
    for (int i = 0; i < 4; ++i) {
      int nl = r4 * 4 + i;
      int dst = (n0 + nl) * D_HID + k0 + c;
      float dr = ts0[c][nl], di = ts1[c][nl];
      wdrT[dst] = f2bf(dr);
      wdiT[dst] = f2bf(di);
      wdnT[dst] = f2bf(-di);
    }
  } else if (z == 5) {
    if (tid == 0) tens[bx] = 0.f;
    int idx4 = (bx * 256 + tid) * 4;
    int m = idx4 >> 10, n = idx4 & 1023;
    float4 hr = *(const float4*)&h_re[idx4];
    float4 hi = *(const float4*)&h_im[idx4];
    short4v br, bi, bm;
    br.x = f2bf(hr.x); br.y = f2bf(hr.y); br.z = f2bf(hr.z); br.w = f2bf(hr.w);
    bi.x = f2bf(hi.x); bi.y = f2bf(hi.y); bi.z = f2bf(hi.z); bi.w = f2bf(hi.w);
    bm.x = f2bf(sqrtf(hr.x * hr.x + hi.x * hi.x));
    bm.y = f2bf(sqrtf(hr.y * hr.y + hi.y * hi.y));
    bm.z = f2bf(sqrtf(hr.z * hr.z + hi.z * hi.z));
    bm.w = f2bf(sqrtf(hr.w * hr.w + hi.w * hi.w));
    *(short4v*)&hbre[idx4] = br;
    *(short4v*)&hbim[idx4] = bi;
    *(short4v*)&gatesA[(size_t)m * 1536 + 512 + n] = bm;
  } else {
    if (bx < 16) {
      int n = (bx & 1) * 256 + tid;
      int kc = bx >> 1;
      float sr = 0.f, si = 0.f;
      for (int i = 0; i < 64; ++i) {
        int k = kc * 64 + i;
        float xv = x[k];
        int idx = k * D_OUT + n;
        sr += xv * (ea_wr[idx] - eg_wr[idx]);
        si += xv * (ea_wi[idx] - eg_wi[idx]);
      }
      bpartr[kc * D_OUT + n] = sr;
      bparti[kc * D_OUT + n] = si;
    } else if (bx < 32) {
      int i = (bx - 16) * 1024 + tid * 4;  // 16 blocks x 1024 = 16384 floats
      *(float4*)&fsbuf[i] = (float4){0.f, 0.f, 0.f, 0.f};
    }
  }
}

// ---------------- MFMA GEMM 1: complex engine, 64x32 tile, BK=64, double-buffered ----
__global__ __launch_bounds__(256) void k_engine(
    const short* __restrict__ hbre, const short* __restrict__ hbim,
    const short* __restrict__ wdrT, const short* __restrict__ wdiT,
    const short* __restrict__ wdnT,
    const float* __restrict__ bpartr, const float* __restrict__ bparti,
    const float* __restrict__ ea_br, const float* __restrict__ ea_bi,
    const float* __restrict__ eg_br, const float* __restrict__ eg_bi,
    float* __restrict__ ore, float* __restrict__ oim,
    short* __restrict__ gatesA, short* __restrict__ candAre, short* __restrict__ candAim,
    float* __restrict__ tens) {
  __shared__ short Ar[2][4096], Ai[2][4096];
  __shared__ short Brs[2][2048], Bis[2][2048], Bns[2][2048];
  const int m0 = blockIdx.x * 64, n0 = blockIdx.y * 32;
  const int tid = threadIdx.x;
  const int wid = tid >> 6, lane = tid & 63;
  const int quad = lane >> 4, lcol = lane & 15;
  const int wm = wid * 16;
  auto stage = [&](int buf, int k0) {
#pragma unroll
    for (int i = 0; i < 2; ++i) {
      int c = i * 256 + tid;
      int kh = c >> 8, row = (c >> 2) & 63, kq = c & 3;
      size_t g = (size_t)(m0 + row) * D_HID + k0 + kh * 32 + kq * 8;
      gl_lds16(hbre + g, &Ar[buf][c * 8]);
      gl_lds16(hbim + g, &Ai[buf][c * 8]);
    }
    {
      int c = tid;
      int kh = c >> 7, row = (c >> 2) & 31, kq = c & 3;
      size_t g = (size_t)(n0 + row) * D_HID + k0 + kh * 32 + kq * 8;
      gl_lds16(wdrT + g, &Brs[buf][c * 8]);
      gl_lds16(wdiT + g, &Bis[buf][c * 8]);
      gl_lds16(wdnT + g, &Bns[buf][c * 8]);
    }
  };
  f32x4 accre[2], accim[2];
#pragma unroll
  for (int nt = 0; nt < 2; ++nt) {
    accre[nt] = (f32x4){0.f, 0.f, 0.f, 0.f};
    accim[nt] = (f32x4){0.f, 0.f, 0.f, 0.f};
  }
  stage(0, 0);
  for (int kt = 0; kt < 16; ++kt) {
    __syncthreads();
    if (kt < 15) stage((kt & 1) ^ 1, (kt + 1) * 64);
    const int buf = kt & 1;
#pragma unroll
    for (int kh = 0; kh < 2; ++kh) {
      bf16x8 ar, ai, br[2], bi[2], bn[2];
      int aoff = kh * 2048 + (wm + lcol) * 32 + quad * 8;
      ar = *(const bf16x8*)&Ar[buf][aoff];
      ai = *(const bf16x8*)&Ai[buf][aoff];
#pragma unroll
      for (int nt = 0; nt < 2; ++nt) {
        int boff = kh * 1024 + (nt * 16 + lcol) * 32 + quad * 8;
        br[nt] = *(const bf16x8*)&Brs[buf][boff];
        bi[nt] = *(const bf16x8*)&Bis[buf][boff];
        bn[nt] = *(const bf16x8*)&Bns[buf][boff];
      }
#pragma unroll
      for (int nt = 0; nt < 2; ++nt) {
        accre[nt] = MFMA16(ar, br[nt], accre[nt]);
        accre[nt] = MFMA16(ai, bn[nt], accre[nt]);
        accim[nt] = MFMA16(ar, bi[nt], accim[nt]);
        accim[nt] = MFMA16(ai, br[nt], accim[nt]);
      }
    }
  }
  // inline bias reduction for this thread's 2 n-columns
  float biasre[2], biasim[2];
#pragma unroll
  for (int nt = 0; nt < 2; ++nt) {
    int n = n0 + nt * 16 + lcol;
    float sr = 0.f, si = 0.f;
#pragma unroll
    for (int kc = 0; kc < 8; ++kc) { sr += bpartr[kc * D_OUT + n]; si += bparti[kc * D_OUT + n]; }
    float brd = ea_br[n] - eg_br[n];
    float bid = ea_bi[n] - eg_bi[n];
    biasre[nt] = sr + brd - bid;
    biasim[nt] = si + brd + bid;
  }
#pragma unroll
  for (int r = 0; r < 4; ++r) {
    int m = m0 + wm + quad * 4 + r;
    float t = 0.f;
#pragma unroll
    for (int nt = 0; nt < 2; ++nt) {
      int n = n0 + nt * 16 + lcol;
      float cre = accre[nt][r] + biasre[nt];
      float cim = accim[nt][r] + biasim[nt];
      t += cre * cre + cim * cim;
      ore[(size_t)m * D_OUT + n] = cre;
      oim[(size_t)m * D_OUT + n] = cim;
      gatesA[(size_t)m * 1536 + n] = f2bf(sqrtf(cre * cre + cim * cim));
      candAre[(size_t)m * 1536 + n] = f2bf(cre);
      candAim[(size_t)m * 1536 + n] = f2bf(cim);
    }
#pragma unroll
    for (int off = 1; off < 16; off <<= 1) t += __shfl_xor(t, off);
    if (lcol == 0) atomicAdd(&tens[m], t * (1.f / 512.f));
  }
}

// ---------------- MFMA GEMM 2: gates (z/r via blockIdx.z), 64x64, BK=64, dbuf ----
__global__ __launch_bounds__(256) void k_gates(
    const short* __restrict__ gatesA,
    const short* __restrict__ gzwT, const short* __restrict__ grwT,
    const float* __restrict__ gz_w, const float* __restrict__ gz_b,
    const float* __restrict__ gr_w, const float* __restrict__ gr_b,
    const float* __restrict__ tens,
    const float* __restrict__ h_re, const float* __restrict__ h_im,
    unsigned short* __restrict__ zbuf,
    short* __restrict__ candAre, short* __restrict__ candAim) {
  __shared__ short As[2][4096];
  __shared__ short Bs[2][4096];
  const int is_z = (blockIdx.z == 0);
  const short* Bt = is_z ? gzwT : grwT;
  const int m0 = blockIdx.x * 64, n0 = blockIdx.y * 64;
  const int tid = threadIdx.x;
  const int wid = tid >> 6, lane = tid & 63;
  const int quad = lane >> 4, lcol = lane & 15;
  const int wm = (wid >> 1) * 32, wn = (wid & 1) * 32;
  auto stage = [&](int buf, int k0) {
#pragma unroll
    for (int i = 0; i < 2; ++i) {
      int c = i * 256 + tid;
      int kh = c >> 8, row = (c >> 2) & 63, kq = c & 3;
      gl_lds16(gatesA + (size_t)(m0 + row) * 1536 + k0 + kh * 32 + kq * 8, &As[buf][c * 8]);
      gl_lds16(Bt + (size_t)(n0 + row) * 1536 + k0 + kh * 32 + kq * 8, &Bs[buf][c * 8]);
    }
  };
  f32x4 acc[2][2];
#pragma unroll
  for (int mt = 0; mt < 2; ++mt)
#pragma unroll
    for (int nt = 0; nt < 2; ++nt) acc[mt][nt] = (f32x4){0.f, 0.f, 0.f, 0.f};
  stage(0, 0);
  for (int kt = 0; kt < 24; ++kt) {
    __syncthreads();
    if (kt < 23) stage((kt & 1) ^ 1, (kt + 1) * 64);
    const int buf = kt & 1;
#pragma unroll
    for (int kh = 0; kh < 2; ++kh) {
      bf16x8 a[2], b[2];
#pragma unroll
      for (int mt = 0; mt < 2; ++mt)
        a[mt] = *(const bf16x8*)&As[buf][kh * 2048 + (wm + mt * 16 + lcol) * 32 + quad * 8];
#pragma unroll
      for (int nt = 0; nt < 2; ++nt)
        b[nt] = *(const bf16x8*)&Bs[buf][kh * 2048 + (wn + nt * 16 + lcol) * 32 + quad * 8];
#pragma unroll
      for (int mt = 0; mt < 2; ++mt)
#pragma unroll
        for (int nt = 0; nt < 2; ++nt)
          acc[mt][nt] = MFMA16(a[mt], b[nt], acc[mt][nt]);
    }
  }
#pragma unroll
  for (int mt = 0; mt < 2; ++mt)
#pragma unroll
    for (int nt = 0; nt < 2; ++nt)
#pragma unroll
      for (int r = 0; r < 4; ++r) {
        int m = m0 + wm + mt * 16 + quad * 4 + r;
        int n = n0 + wn + nt * 16 + lcol;
        float tv = tens[m];
        if (is_z) {
          float zp = acc[mt][nt][r] + gz_b[n] + tv * gz_w[(size_t)512 * D_HID + n];
          zbuf[(size_t)m * D_HID + n] = (unsigned short)f2bf(1.f / (1.f + expf(-zp)));
        } else {
          float rp = acc[mt][nt][r] + gr_b[n] + tv * gr_w[(size_t)512 * D_HID + n];
          float rr = 1.f / (1.f + expf(-rp));
          candAre[(size_t)m * 1536 + 512 + n] = f2bf(rr * h_re[(size_t)m * D_HID + n]);
          candAim[(size_t)m * 1536 + 512 + n] = f2bf(rr * h_im[(size_t)m * D_HID + n]);
        }
      }
}

// ---------------- MFMA GEMM 3: candidate + GRU blend, 64x64, BK=64, dbuf ----
__global__ __launch_bounds__(256) void k_cand(
    const short* __restrict__ candAre, const short* __restrict__ candAim,
    const short* __restrict__ ghrwT, const short* __restrict__ ghiwT,
    const float* __restrict__ ghr_b, const float* __restrict__ ghi_b,
    const float* __restrict__ ghr_w,
    const float* __restrict__ tens, const unsigned short* __restrict__ zbuf,
    const float* __restrict__ h_re, const float* __restrict__ h_im,
    float* __restrict__ nhre, float* __restrict__ nhim) {
  __shared__ short As[2][4096];
  __shared__ short Bs[2][4096];
  const int is_re = (blockIdx.z == 0);
  const short* A = is_re ? candAre : candAim;
  const short* Bt = is_re ? ghrwT : ghiwT;
  const float* bias = is_re ? ghr_b : ghi_b;
  const float* h = is_re ? h_re : h_im;
  float* outp = is_re ? nhre : nhim;
  const int m0 = blockIdx.x * 64, n0 = blockIdx.y * 64;
  const int tid = threadIdx.x;
  const int wid = tid >> 6, lane = tid & 63;
  const int quad = lane >> 4, lcol = lane & 15;
  const int wm = (wid >> 1) * 32, wn = (wid & 1) * 32;
  auto stage = [&](int buf, int k0) {
#pragma unroll
    for (int i = 0; i < 2; ++i) {
      int c = i * 256 + tid;
      int kh = c >> 8, row = (c >> 2) & 63, kq = c & 3;
      gl_lds16(A + (size_t)(m0 + row) * 1536 + k0 + kh * 32 + kq * 8, &As[buf][c * 8]);
      gl_lds16(Bt + (size_t)(n0 + row) * 1536 + k0 + kh * 32 + kq * 8, &Bs[buf][c * 8]);
    }
  };
  f32x4 acc[2][2];
#pragma unroll
  for (int mt = 0; mt < 2; ++mt)
#pragma unroll
    for (int nt = 0; nt < 2; ++nt) acc[mt][nt] = (f32x4){0.f, 0.f, 0.f, 0.f};
  stage(0, 0);
  for (int kt = 0; kt < 24; ++kt) {
    __syncthreads();
    if (kt < 23) stage((kt & 1) ^ 1, (kt + 1) * 64);
    const int buf = kt & 1;
#pragma unroll
    for (int kh = 0; kh < 2; ++kh) {
      bf16x8 a[2], b[2];
#pragma unroll
      for (int mt = 0; mt < 2; ++mt)
        a[mt] = *(const bf16x8*)&As[buf][kh * 2048 + (wm + mt * 16 + lcol) * 32 + quad * 8];
#pragma unroll
      for (int nt = 0; nt < 2; ++nt)
        b[nt] = *(const bf16x8*)&Bs[buf][kh * 2048 + (wn + nt * 16 + lcol) * 32 + quad * 8];
#pragma unroll
      for (int mt = 0; mt < 2; ++mt)
#pragma unroll
        for (int nt = 0; nt < 2; ++nt)
          acc[mt][nt] = MFMA16(a[mt], b[nt], acc[mt][nt]);
    }
  }
#pragma unroll
  for (int mt = 0; mt < 2; ++mt)
#pragma unroll
    for (int nt = 0; nt < 2; ++nt)
#pragma unroll
      for (int r = 0; r < 4; ++r) {
        int m = m0 + wm + mt * 16 + quad * 4 + r;
        int n = n0 + wn + nt * 16 + lcol;
        float pre = acc[mt][nt][r] + bias[n];
        if (is_re) pre += tens[m] * ghr_w[(size_t)512 * D_HID + n];
        float cand = tanhf(pre);
        float z = bf2f(zbuf[(size_t)m * D_HID + n]);
        float hv = h[(size_t)m * D_HID + n];
        outp[(size_t)m * D_HID + n] = (1.f - z) * hv + z * cand;
      }
}

// ---------------- faction sums: atomic into fs[comp][n*8+f] ----------------
__global__ __launch_bounds__(256) void k_fsum_part(
    const float* __restrict__ nhre, const float* __restrict__ nhim,
    float* __restrict__ fsbuf) {
  int f = blockIdx.x >> 3, rc = blockIdx.x & 7, comp = blockIdx.y;
  const float* src = comp ? nhim : nhre;
  float* fs = fsbuf + (size_t)comp * 8192;
  int row0 = f * 256 + rc * 32;
#pragma unroll
  for (int nc = 0; nc < 4; ++nc) {
    int n = nc * 256 + threadIdx.x;
    float s = 0.f;
    const float* base = src + (size_t)row0 * D_HID + n;
    for (int j = 0; j < 32; ++j) s += base[(size_t)j * D_HID];
    atomicAdd(&fs[(size_t)n * 8 + f], s);
  }
}

// ---------------- sync (faction mean + inline global mean) ----------------
__global__ __launch_bounds__(256) void k_sync(
    float* __restrict__ nhre, float* __restrict__ nhim,
    const float* __restrict__ fsbuf, const int* __restrict__ step) {
  int idx = blockIdx.x * 256 + threadIdx.x;
  int m = idx >> 10, n = idx & 1023;
  int f = m >> 8;
  const float* f0 = fsbuf + (size_t)n * 8;
  const float* f1 = fsbuf + 8192 + (size_t)n * 8;
  float gr = 0.f, gi = 0.f;
#pragma unroll
  for (int ff = 0; ff < 8; ++ff) { gr += f0[ff]; gi += f1[ff]; }
  float fr = f0[f], fi = f1[f];
  float vr = nhre[idx], vi = nhim[idx];
  vr = 0.85f * vr + 0.15f * (fr * (1.f / 256.f));
  vi = 0.85f * vi + 0.15f * (fi * (1.f / 256.f));
  if (step[0] > 5 && (m & 255) < 64) {
    vr = 0.85f * vr + 0.15f * (gr * (1.f / 2048.f));
    vi = 0.85f * vi + 0.15f * (gi * (1.f / 2048.f));
  }
  nhre[idx] = vr;
  nhim[idx] = vi;
}

// ---------------- softmax stats ----------------
__global__ __launch_bounds__(1024) void k_stats(
    const float* __restrict__ tens, float* __restrict__ wsoft,
    float* __restrict__ meanT_out) {
  __shared__ float red[16];
  __shared__ float s_max, s_sum;
  int tid = threadIdx.x;
  int wid = tid >> 6, lane = tid & 63;
  float a = tens[tid], b = tens[tid + 1024];
  float mx = fmaxf(a, b);
  for (int off = 32; off; off >>= 1) mx = fmaxf(mx, __shfl_down(mx, off));
  if (lane == 0) red[wid] = mx;
  __syncthreads();
  if (tid == 0) {
    float m2 = red[0];
    for (int i = 1; i < 16; ++i) m2 = fmaxf(m2, red[i]);
    s_max = m2;
  }
  __syncthreads();
  float mxv = s_max;
  float ea = expf(a - mxv), eb = expf(b - mxv);
  float se = ea + eb;
  for (int off = 32; off; off >>= 1) se += __shfl_down(se, off);
  __syncthreads();
  if (lane == 0) red[wid] = se;
  __syncthreads();
  if (tid == 0) {
    float s2 = 0.f;
    for (int i = 0; i < 16; ++i) s2 += red[i];
    s_sum = s2;
  }
  __syncthreads();
  float inv = 1.f / s_sum;
  wsoft[tid] = ea * inv;
  wsoft[tid + 1024] = eb * inv;
  float st = a + b;
  for (int off = 32; off; off >>= 1) st += __shfl_down(st, off);
  __syncthreads();
  if (lane == 0) red[wid] = st;
  __syncthreads();
  if (tid == 0) {
    float s2 = 0.f;
    for (int i = 0; i < 16; ++i) s2 += red[i];
    meanT_out[0] = s2 * (1.f / 2048.f);
  }
}

// ---------------- combine stage1 ----------------
__global__ __launch_bounds__(256) void k_comb_part(
    const float* __restrict__ ore, const float* __restrict__ oim,
    const float* __restrict__ wsoft, float* __restrict__ cpart) {
  int j = blockIdx.x * 256 + threadIdx.x;
  int mc = blockIdx.y;
  const float* src = (j < 512) ? ore : oim;
  int col = j & 511;
  float s = 0.f;
  for (int i = 0; i < 128; ++i) {
    int m = mc * 128 + i;
    s += wsoft[m] * src[(size_t)m * D_OUT + col];
  }
  cpart[(size_t)mc * 1024 + j] = s;
}

// ---------------- pred stage1 (comb reduction fused in) ----------------
__global__ __launch_bounds__(256) void k_pred_part(
    const float* __restrict__ cpart, const float* __restrict__ oh_w,
    float* __restrict__ ppart) {
  __shared__ float combs[128];
  int tid = threadIdx.x;
  int jc = blockIdx.y;
  if (tid < 128) {
    float s = 0.f;
#pragma unroll
    for (int mc = 0; mc < 16; ++mc) s += cpart[(size_t)mc * 1024 + jc * 128 + tid];
    combs[tid] = s;
  }
  __syncthreads();
  int n = blockIdx.x * 256 + tid;
  float s = 0.f;
  for (int i = 0; i < 128; ++i)
    s += combs[i] * oh_w[(size_t)(jc * 128 + i) * D_IN + n];
  ppart[(size_t)jc * D_IN + n] = s;
}

__global__ __launch_bounds__(256) void k_pred_red(
    const float* __restrict__ ppart, const float* __restrict__ oh_b,
    float* __restrict__ pred) {
  int n = blockIdx.x * 256 + threadIdx.x;
  float s = oh_b[n];
#pragma unroll
  for (int jc = 0; jc < 8; ++jc) s += ppart[(size_t)jc * D_IN + n];
  pred[n] = s;
}

// ---------------- launcher ----------------
extern "C" void kernel_launch(void* const* d_in, const int* in_sizes, int n_in,
                              void* d_out, int out_size, void* d_ws, size_t ws_size,
                              hipStream_t stream) {
  const float* x     = (const float*)d_in[0];
  const float* h_re  = (const float*)d_in[1];
  const float* h_im  = (const float*)d_in[2];
  const float* ea_wr = (const float*)d_in[3];
  const float* ea_br = (const float*)d_in[4];
  const float* ea_wi = (const float*)d_in[5];
  const float* ea_bi = (const float*)d_in[6];
  const float* eg_wr = (const float*)d_in[7];
  const float* eg_br = (const float*)d_in[8];
  const float* eg_wi = (const float*)d_in[9];
  const float* eg_bi = (const float*)d_in[10];
  const float* gz_w  = (const float*)d_in[11];
  const float* gz_b  = (const float*)d_in[12];
  const float* gr_w  = (const float*)d_in[13];
  const float* gr_b  = (const float*)d_in[14];
  const float* ghr_w = (const float*)d_in[15];
  const float* ghr_b = (const float*)d_in[16];
  const float* ghi_w = (const float*)d_in[17];
  const float* ghi_b = (const float*)d_in[18];
  const float* oh_w  = (const float*)d_in[19];
  const float* oh_b  = (const float*)d_in[20];
  const int*   step  = (const int*)d_in[21];

  float* out = (float*)d_out;
  float* pred_out  = out;
  float* meanT_out = out + 512;
  float* nhre_out  = out + 513;
  float* nhim_out  = out + 513 + N_CELLS * D_HID;

  char* p = (char*)d_ws;
  auto carve = [&](size_t bytes) { char* r = p; p += (bytes + 255) & ~(size_t)255; return r; };
  short* wdrT   = (short*)carve(512 * 1024 * 2);
  short* wdiT   = (short*)carve(512 * 1024 * 2);
  short* wdnT   = (short*)carve(512 * 1024 * 2);
  short* gzwT   = (short*)carve(1024 * 1536 * 2);
  short* grwT   = (short*)carve(1024 * 1536 * 2);
  short* ghrwT  = (short*)carve(1024 * 1536 * 2);
  short* ghiwT  = (short*)carve(1024 * 1536 * 2);
  short* hbre   = (short*)carve(2048 * 1024 * 2);
  short* hbim   = (short*)carve(2048 * 1024 * 2);
  short* gatesA = (short*)carve((size_t)2048 * 1536 * 2);
  short* candAre= (short*)carve((size_t)2048 * 1536 * 2);
  short* candAim= (short*)carve((size_t)2048 * 1536 * 2);
  float* ore    = (float*)carve(2048 * 512 * 4);
  float* oim    = (float*)carve(2048 * 512 * 4);
  unsigned short* zbuf = (unsigned short*)carve((size_t)2048 * 1024 * 2);
  float* bpartr = (float*)carve(8 * 512 * 4);
  float* bparti = (float*)carve(8 * 512 * 4);
  float* tens   = (float*)carve(2048 * 4);
  float* fsbuf  = (float*)carve(2 * 8192 * 4);
  float* wsoft  = (float*)carve(2048 * 4);
  float* cpart  = (float*)carve(16 * 1024 * 4);
  float* ppart  = (float*)carve(8 * 512 * 4);

  hipLaunchKernelGGL(k_prep_all, dim3(2048, 1, 7), dim3(256), 0, stream,
                     gz_w, gr_w, ghr_w, ghi_w, gzwT, grwT, ghrwT, ghiwT,
                     ea_wr, eg_wr, ea_wi, eg_wi, wdrT, wdiT, wdnT,
                     h_re, h_im, hbre, hbim, gatesA, tens,
                     x, bpartr, bparti, fsbuf);
  hipLaunchKernelGGL(k_engine, dim3(32, 16), dim3(256), 0, stream,
                     hbre, hbim, wdrT, wdiT, wdnT,
                     bpartr, bparti, ea_br, ea_bi, eg_br, eg_bi,
                     ore, oim, gatesA, candAre, candAim, tens);
  hipLaunchKernelGGL(k_gates, dim3(32, 16, 2), dim3(256), 0, stream,
                     gatesA, gzwT, grwT, gz_w, gz_b, gr_w, gr_b, tens,
                     h_re, h_im, zbuf, candAre, candAim);
  hipLaunchKernelGGL(k_cand, dim3(32, 16, 2), dim3(256), 0, stream,
                     candAre, candAim, ghrwT, ghiwT, ghr_b, ghi_b, ghr_w,
                     tens, zbuf, h_re, h_im, nhre_out, nhim_out);
  hipLaunchKernelGGL(k_fsum_part, dim3(64, 2), dim3(256), 0, stream,
                     nhre_out, nhim_out, fsbuf);
  hipLaunchKernelGGL(k_sync, dim3((N_CELLS * D_HID) / 256), dim3(256), 0, stream,
                     nhre_out, nhim_out, fsbuf, step);
  hipLaunchKernelGGL(k_stats, dim3(1), dim3(1024), 0, stream, tens, wsoft, meanT_out);
  hipLaunchKernelGGL(k_comb_part, dim3(4, 16), dim3(256), 0, stream,
                     ore, oim, wsoft, cpart);
  hipLaunchKernelGGL(k_pred_part, dim3(2, 8), dim3(256), 0, stream, cpart, oh_w, ppart);
  hipLaunchKernelGGL(k_pred_red, dim3(2), dim3(256), 0, stream, ppart, oh_b, pred_out);
}

// Round 8
// 283.681 us; speedup vs baseline: 1.0256x; 1.0256x over previous
//
#include <hip/hip_runtime.h>
#include <math.h>

#define N_CELLS 2048
#define D_IN 512
#define D_HID 1024
#define D_OUT 512

typedef __attribute__((ext_vector_type(8))) short bf16x8;
typedef __attribute__((ext_vector_type(4))) float f32x4;
typedef __attribute__((ext_vector_type(4))) short short4v;

#define MFMA16(a, b, c) __builtin_amdgcn_mfma_f32_16x16x32_bf16(a, b, c, 0, 0, 0)

__device__ __forceinline__ short f2bf(float f) {
  union { float f; unsigned u; } v; v.f = f;
  unsigned r = (v.u + 0x7FFFu + ((v.u >> 16) & 1u)) >> 16;
  return (short)r;
}

__device__ __forceinline__ float bf2f(unsigned short u) {
  union { unsigned u; float f; } v; v.u = ((unsigned)u) << 16; return v.f;
}

__device__ __forceinline__ void gl_lds16(const void* g, void* l) {
  __builtin_amdgcn_global_load_lds(
      (const __attribute__((address_space(1))) void*)g,
      (__attribute__((address_space(3))) void*)l, 16, 0, 0);
}

// ---------------- prep: ALL independent prep work, flat grid of 8736 blocks ----
// [0,6144)    : gate weight transposes (4 weights x 1536 tiles)
// [6144,6656) : wd transpose (512 tiles)
// [6656,8704) : h fp32->bf16 + |h| ; zero tens (2048 blocks)
// [8704,8720) : bias partials (16 blocks)
// [8720,8736) : zero fs accumulators (16 blocks)
__global__ __launch_bounds__(256) void k_prep_all(
    const float* __restrict__ w0, const float* __restrict__ w1,
    const float* __restrict__ w2, const float* __restrict__ w3,
    short* __restrict__ t0, short* __restrict__ t1,
    short* __restrict__ t2, short* __restrict__ t3,
    const float* __restrict__ ea_wr, const float* __restrict__ eg_wr,
    const float* __restrict__ ea_wi, const float* __restrict__ eg_wi,
    short* __restrict__ wdrT, short* __restrict__ wdiT, short* __restrict__ wdnT,
    const float* __restrict__ h_re, const float* __restrict__ h_im,
    short* __restrict__ hbre, short* __restrict__ hbim, short* __restrict__ gatesA,
    float* __restrict__ tens,
    const float* __restrict__ x,
    float* __restrict__ bpartr, float* __restrict__ bparti,
    float* __restrict__ fsbuf) {
  __shared__ float ts0[32][33], ts1[32][33];
  const int bx = blockIdx.x;
  const int tid = threadIdx.x;
  if (bx < 6144) {
    const int z = bx / 1536, idx = bx % 1536;
    const int xx = idx % 48, yy = idx / 48;
    const float* w = (z == 0) ? w0 : (z == 1) ? w1 : (z == 2) ? w2 : w3;
    short* wT = (z == 0) ? t0 : (z == 1) ? t1 : (z == 2) ? t2 : t3;
    const int k0 = xx * 32, n0 = yy * 32;
    const int c = tid & 31, r4 = tid >> 5;
#pragma unroll
    for (int i = 0; i < 4; ++i) {
      int kl = r4 * 4 + i;
      int k = k0 + kl;
      int srcrow = (k < 512) ? k : k + 1;
      ts0[kl][c] = w[(size_t)srcrow * D_HID + n0 + c];
    }
    __syncthreads();
#pragma unroll
    for (int i = 0; i < 4; ++i) {
      int nl = r4 * 4 + i;
      wT[(size_t)(n0 + nl) * 1536 + k0 + c] = f2bf(ts0[c][nl]);
    }
  } else if (bx < 6656) {
    const int idx = bx - 6144;
    const int xx = idx & 31, yy = idx >> 5;  // xx: 32 k-tiles, yy: 16 n-tiles
    const int k0 = xx * 32, n0 = yy * 32;
    const int c = tid & 31, r4 = tid >> 5;
#pragma unroll
    for (int i = 0; i < 4; ++i) {
      int kl = r4 * 4 + i;
      int src = (512 + k0 + kl) * D_OUT + n0 + c;
      ts0[kl][c] = ea_wr[src] - eg_wr[src];
      ts1[kl][c] = ea_wi[src] - eg_wi[src];
    }
    __syncthreads();
#pragma unroll
    for (int i = 0; i < 4; ++i) {
      int nl = r4 * 4 + i;
      int dst = (n0 + nl) * D_HID + k0 + c;
      float dr = ts0[c][nl], di = ts1[c][nl];
      wdrT[dst] = f2bf(dr);
      wdiT[dst] = f2bf(di);
      wdnT[dst] = f2bf(-di);
    }
  } else if (bx < 8704) {
    const int idx = bx - 6656;
    if (tid == 0) tens[idx] = 0.f;
    int idx4 = (idx * 256 + tid) * 4;
    int m = idx4 >> 10, n = idx4 & 1023;
    float4 hr = *(const float4*)&h_re[idx4];
    float4 hi = *(const float4*)&h_im[idx4];
    short4v br, bi, bm;
    br.x = f2bf(hr.x); br.y = f2bf(hr.y); br.z = f2bf(hr.z); br.w = f2bf(hr.w);
    bi.x = f2bf(hi.x); bi.y = f2bf(hi.y); bi.z = f2bf(hi.z); bi.w = f2bf(hi.w);
    bm.x = f2bf(sqrtf(hr.x * hr.x + hi.x * hi.x));
    bm.y = f2bf(sqrtf(hr.y * hr.y + hi.y * hi.y));
    bm.z = f2bf(sqrtf(hr.z * hr.z + hi.z * hi.z));
    bm.w = f2bf(sqrtf(hr.w * hr.w + hi.w * hi.w));
    *(short4v*)&hbre[idx4] = br;
    *(short4v*)&hbim[idx4] = bi;
    *(short4v*)&gatesA[(size_t)m * 1536 + 512 + n] = bm;
  } else if (bx < 8720) {
    const int idx = bx - 8704;
    int n = (idx & 1) * 256 + tid;
    int kc = idx >> 1;
    float sr = 0.f, si = 0.f;
    for (int i = 0; i < 64; ++i) {
      int k = kc * 64 + i;
      float xv = x[k];
      int j = k * D_OUT + n;
      sr += xv * (ea_wr[j] - eg_wr[j]);
      si += xv * (ea_wi[j] - eg_wi[j]);
    }
    bpartr[kc * D_OUT + n] = sr;
    bparti[kc * D_OUT + n] = si;
  } else {
    const int idx = bx - 8720;
    int i = idx * 1024 + tid * 4;
    *(float4*)&fsbuf[i] = (float4){0.f, 0.f, 0.f, 0.f};
  }
}

// ---------------- MFMA GEMM 1: complex engine (tile 64x32, BK=64, single-buffer) ----
__global__ __launch_bounds__(256) void k_engine(
    const short* __restrict__ hbre, const short* __restrict__ hbim,
    const short* __restrict__ wdrT, const short* __restrict__ wdiT,
    const short* __restrict__ wdnT,
    const float* __restrict__ bpartr, const float* __restrict__ bparti,
    const float* __restrict__ ea_br, const float* __restrict__ ea_bi,
    const float* __restrict__ eg_br, const float* __restrict__ eg_bi,
    float* __restrict__ ore, float* __restrict__ oim,
    short* __restrict__ gatesA, short* __restrict__ candAre, short* __restrict__ candAim,
    float* __restrict__ tens) {
  __shared__ short Ar[2 * 64 * 32], Ai[2 * 64 * 32];
  __shared__ short Brs[2 * 32 * 32], Bis[2 * 32 * 32], Bns[2 * 32 * 32];
  const int m0 = blockIdx.x * 64, n0 = blockIdx.y * 32;
  const int tid = threadIdx.x;
  const int wid = tid >> 6, lane = tid & 63;
  const int quad = lane >> 4, lcol = lane & 15;
  const int wm = wid * 16;
  f32x4 accre[2], accim[2];
#pragma unroll
  for (int nt = 0; nt < 2; ++nt) {
    accre[nt] = (f32x4){0.f, 0.f, 0.f, 0.f};
    accim[nt] = (f32x4){0.f, 0.f, 0.f, 0.f};
  }
  for (int k0 = 0; k0 < D_HID; k0 += 64) {
    if (k0) __syncthreads();
#pragma unroll
    for (int i = 0; i < 2; ++i) {
      int c = i * 256 + tid;  // 0..511
      int kh = c >> 8, row = (c >> 2) & 63, kq = c & 3;
      size_t g = (size_t)(m0 + row) * D_HID + k0 + kh * 32 + kq * 8;
      gl_lds16(hbre + g, &Ar[c * 8]);
      gl_lds16(hbim + g, &Ai[c * 8]);
    }
    {
      int c = tid;  // 0..255
      int kh = c >> 7, row = (c >> 2) & 31, kq = c & 3;
      size_t g = (size_t)(n0 + row) * D_HID + k0 + kh * 32 + kq * 8;
      gl_lds16(wdrT + g, &Brs[c * 8]);
      gl_lds16(wdiT + g, &Bis[c * 8]);
      gl_lds16(wdnT + g, &Bns[c * 8]);
    }
    __syncthreads();
#pragma unroll
    for (int kh = 0; kh < 2; ++kh) {
      bf16x8 ar, ai, br[2], bi[2], bn[2];
      int aoff = kh * 2048 + (wm + lcol) * 32 + quad * 8;
      ar = *(const bf16x8*)&Ar[aoff];
      ai = *(const bf16x8*)&Ai[aoff];
#pragma unroll
      for (int nt = 0; nt < 2; ++nt) {
        int boff = kh * 1024 + (nt * 16 + lcol) * 32 + quad * 8;
        br[nt] = *(const bf16x8*)&Brs[boff];
        bi[nt] = *(const bf16x8*)&Bis[boff];
        bn[nt] = *(const bf16x8*)&Bns[boff];
      }
#pragma unroll
      for (int nt = 0; nt < 2; ++nt) {
        accre[nt] = MFMA16(ar, br[nt], accre[nt]);
        accre[nt] = MFMA16(ai, bn[nt], accre[nt]);
        accim[nt] = MFMA16(ar, bi[nt], accim[nt]);
        accim[nt] = MFMA16(ai, br[nt], accim[nt]);
      }
    }
  }
  // inline bias reduction for this thread's 2 n-columns
  float biasre[2], biasim[2];
#pragma unroll
  for (int nt = 0; nt < 2; ++nt) {
    int n = n0 + nt * 16 + lcol;
    float sr = 0.f, si = 0.f;
#pragma unroll
    for (int kc = 0; kc < 8; ++kc) { sr += bpartr[kc * D_OUT + n]; si += bparti[kc * D_OUT + n]; }
    float brd = ea_br[n] - eg_br[n];
    float bid = ea_bi[n] - eg_bi[n];
    biasre[nt] = sr + brd - bid;
    biasim[nt] = si + brd + bid;
  }
#pragma unroll
  for (int r = 0; r < 4; ++r) {
    int m = m0 + wm + quad * 4 + r;
    float t = 0.f;
#pragma unroll
    for (int nt = 0; nt < 2; ++nt) {
      int n = n0 + nt * 16 + lcol;
      float cre = accre[nt][r] + biasre[nt];
      float cim = accim[nt][r] + biasim[nt];
      t += cre * cre + cim * cim;
      ore[(size_t)m * D_OUT + n] = cre;
      oim[(size_t)m * D_OUT + n] = cim;
      gatesA[(size_t)m * 1536 + n] = f2bf(sqrtf(cre * cre + cim * cim));
      candAre[(size_t)m * 1536 + n] = f2bf(cre);
      candAim[(size_t)m * 1536 + n] = f2bf(cim);
    }
#pragma unroll
    for (int off = 1; off < 16; off <<= 1) t += __shfl_xor(t, off);
    if (lcol == 0) atomicAdd(&tens[m], t * (1.f / 512.f));
  }
}

// ---------------- MFMA GEMM 2: gates (z/r via blockIdx.z), 64x64, BK=64, single-buffer ----
__global__ __launch_bounds__(256) void k_gates(
    const short* __restrict__ gatesA,
    const short* __restrict__ gzwT, const short* __restrict__ grwT,
    const float* __restrict__ gz_w, const float* __restrict__ gz_b,
    const float* __restrict__ gr_w, const float* __restrict__ gr_b,
    const float* __restrict__ tens,
    const float* __restrict__ h_re, const float* __restrict__ h_im,
    unsigned short* __restrict__ zbuf,
    short* __restrict__ candAre, short* __restrict__ candAim) {
  __shared__ short As[2 * 64 * 32];
  __shared__ short Bs[2 * 64 * 32];
  const int is_z = (blockIdx.z == 0);
  const short* Bt = is_z ? gzwT : grwT;
  const int m0 = blockIdx.x * 64, n0 = blockIdx.y * 64;
  const int tid = threadIdx.x;
  const int wid = tid >> 6, lane = tid & 63;
  const int quad = lane >> 4, lcol = lane & 15;
  const int wm = (wid >> 1) * 32, wn = (wid & 1) * 32;
  f32x4 acc[2][2];
#pragma unroll
  for (int mt = 0; mt < 2; ++mt)
#pragma unroll
    for (int nt = 0; nt < 2; ++nt) acc[mt][nt] = (f32x4){0.f, 0.f, 0.f, 0.f};
  for (int k0 = 0; k0 < 1536; k0 += 64) {
    if (k0) __syncthreads();
#pragma unroll
    for (int i = 0; i < 2; ++i) {
      int c = i * 256 + tid;
      int kh = c >> 8, row = (c >> 2) & 63, kq = c & 3;
      gl_lds16(gatesA + (size_t)(m0 + row) * 1536 + k0 + kh * 32 + kq * 8, &As[c * 8]);
      gl_lds16(Bt + (size_t)(n0 + row) * 1536 + k0 + kh * 32 + kq * 8, &Bs[c * 8]);
    }
    __syncthreads();
#pragma unroll
    for (int kh = 0; kh < 2; ++kh) {
      bf16x8 a[2], b[2];
#pragma unroll
      for (int mt = 0; mt < 2; ++mt)
        a[mt] = *(const bf16x8*)&As[kh * 2048 + (wm + mt * 16 + lcol) * 32 + quad * 8];
#pragma unroll
      for (int nt = 0; nt < 2; ++nt)
        b[nt] = *(const bf16x8*)&Bs[kh * 2048 + (wn + nt * 16 + lcol) * 32 + quad * 8];
#pragma unroll
      for (int mt = 0; mt < 2; ++mt)
#pragma unroll
        for (int nt = 0; nt < 2; ++nt)
          acc[mt][nt] = MFMA16(a[mt], b[nt], acc[mt][nt]);
    }
  }
#pragma unroll
  for (int mt = 0; mt < 2; ++mt)
#pragma unroll
    for (int nt = 0; nt < 2; ++nt)
#pragma unroll
      for (int r = 0; r < 4; ++r) {
        int m = m0 + wm + mt * 16 + quad * 4 + r;
        int n = n0 + wn + nt * 16 + lcol;
        float tv = tens[m];
        if (is_z) {
          float zp = acc[mt][nt][r] + gz_b[n] + tv * gz_w[(size_t)512 * D_HID + n];
          zbuf[(size_t)m * D_HID + n] = (unsigned short)f2bf(1.f / (1.f + expf(-zp)));
        } else {
          float rp = acc[mt][nt][r] + gr_b[n] + tv * gr_w[(size_t)512 * D_HID + n];
          float rr = 1.f / (1.f + expf(-rp));
          candAre[(size_t)m * 1536 + 512 + n] = f2bf(rr * h_re[(size_t)m * D_HID + n]);
          candAim[(size_t)m * 1536 + 512 + n] = f2bf(rr * h_im[(size_t)m * D_HID + n]);
        }
      }
}

// ---------------- MFMA GEMM 3: candidate + GRU blend, 64x64, BK=64, single-buffer ----
__global__ __launch_bounds__(256) void k_cand(
    const short* __restrict__ candAre, const short* __restrict__ candAim,
    const short* __restrict__ ghrwT, const short* __restrict__ ghiwT,
    const float* __restrict__ ghr_b, const float* __restrict__ ghi_b,
    const float* __restrict__ ghr_w,
    const float* __restrict__ tens, const unsigned short* __restrict__ zbuf,
    const float* __restrict__ h_re, const float* __restrict__ h_im,
    float* __restrict__ nhre, float* __restrict__ nhim) {
  __shared__ short As[2 * 64 * 32];
  __shared__ short Bs[2 * 64 * 32];
  const int is_re = (blockIdx.z == 0);
  const short* A = is_re ? candAre : candAim;
  const short* Bt = is_re ? ghrwT : ghiwT;
  const float* bias = is_re ? ghr_b : ghi_b;
  const float* h = is_re ? h_re : h_im;
  float* outp = is_re ? nhre : nhim;
  const int m0 = blockIdx.x * 64, n0 = blockIdx.y * 64;
  const int tid = threadIdx.x;
  const int wid = tid >> 6, lane = tid & 63;
  const int quad = lane >> 4, lcol = lane & 15;
  const int wm = (wid >> 1) * 32, wn = (wid & 1) * 32;
  f32x4 acc[2][2];
#pragma unroll
  for (int mt = 0; mt < 2; ++mt)
#pragma unroll
    for (int nt = 0; nt < 2; ++nt) acc[mt][nt] = (f32x4){0.f, 0.f, 0.f, 0.f};
  for (int k0 = 0; k0 < 1536; k0 += 64) {
    if (k0) __syncthreads();
#pragma unroll
    for (int i = 0; i < 2; ++i) {
      int c = i * 256 + tid;
      int kh = c >> 8, row = (c >> 2) & 63, kq = c & 3;
      gl_lds16(A + (size_t)(m0 + row) * 1536 + k0 + kh * 32 + kq * 8, &As[c * 8]);
      gl_lds16(Bt + (size_t)(n0 + row) * 1536 + k0 + kh * 32 + kq * 8, &Bs[c * 8]);
    }
    __syncthreads();
#pragma unroll
    for (int kh = 0; kh < 2; ++kh) {
      bf16x8 a[2], b[2];
#pragma unroll
      for (int mt = 0; mt < 2; ++mt)
        a[mt] = *(const bf16x8*)&As[kh * 2048 + (wm + mt * 16 + lcol) * 32 + quad * 8];
#pragma unroll
      for (int nt = 0; nt < 2; ++nt)
        b[nt] = *(const bf16x8*)&Bs[kh * 2048 + (wn + nt * 16 + lcol) * 32 + quad * 8];
#pragma unroll
      for (int mt = 0; mt < 2; ++mt)
#pragma unroll
        for (int nt = 0; nt < 2; ++nt)
          acc[mt][nt] = MFMA16(a[mt], b[nt], acc[mt][nt]);
    }
  }
#pragma unroll
  for (int mt = 0; mt < 2; ++mt)
#pragma unroll
    for (int nt = 0; nt < 2; ++nt)
#pragma unroll
      for (int r = 0; r < 4; ++r) {
        int m = m0 + wm + mt * 16 + quad * 4 + r;
        int n = n0 + wn + nt * 16 + lcol;
        float pre = acc[mt][nt][r] + bias[n];
        if (is_re) pre += tens[m] * ghr_w[(size_t)512 * D_HID + n];
        float cand = tanhf(pre);
        float z = bf2f(zbuf[(size_t)m * D_HID + n]);
        float hv = h[(size_t)m * D_HID + n];
        outp[(size_t)m * D_HID + n] = (1.f - z) * hv + z * cand;
      }
}

// ---------------- faction sums: atomic into fs[comp][n*8+f] ----------------
__global__ __launch_bounds__(256) void k_fsum_part(
    const float* __restrict__ nhre, const float* __restrict__ nhim,
    float* __restrict__ fsbuf) {
  int f = blockIdx.x >> 3, rc = blockIdx.x & 7, comp = blockIdx.y;
  const float* src = comp ? nhim : nhre;
  float* fs = fsbuf + (size_t)comp * 8192;
  int row0 = f * 256 + rc * 32;
#pragma unroll
  for (int nc = 0; nc < 4; ++nc) {
    int n = nc * 256 + threadIdx.x;
    float s = 0.f;
    const float* base = src + (size_t)row0 * D_HID + n;
    for (int j = 0; j < 32; ++j) s += base[(size_t)j * D_HID];
    atomicAdd(&fs[(size_t)n * 8 + f], s);
  }
}

// ---------------- sync (faction mean + inline global mean) ----------------
__global__ __launch_bounds__(256) void k_sync(
    float* __restrict__ nhre, float* __restrict__ nhim,
    const float* __restrict__ fsbuf, const int* __restrict__ step) {
  int idx = blockIdx.x * 256 + threadIdx.x;
  int m = idx >> 10, n = idx & 1023;
  int f = m >> 8;
  const float* f0 = fsbuf + (size_t)n * 8;
  const float* f1 = fsbuf + 8192 + (size_t)n * 8;
  float gr = 0.f, gi = 0.f;
#pragma unroll
  for (int ff = 0; ff < 8; ++ff) { gr += f0[ff]; gi += f1[ff]; }
  float fr = f0[f], fi = f1[f];
  float vr = nhre[idx], vi = nhim[idx];
  vr = 0.85f * vr + 0.15f * (fr * (1.f / 256.f));
  vi = 0.85f * vi + 0.15f * (fi * (1.f / 256.f));
  if (step[0] > 5 && (m & 255) < 64) {
    vr = 0.85f * vr + 0.15f * (gr * (1.f / 2048.f));
    vi = 0.85f * vi + 0.15f * (gi * (1.f / 2048.f));
  }
  nhre[idx] = vr;
  nhim[idx] = vi;
}

// ---------------- softmax stats ----------------
__global__ __launch_bounds__(1024) void k_stats(
    const float* __restrict__ tens, float* __restrict__ wsoft,
    float* __restrict__ meanT_out) {
  __shared__ float red[16];
  __shared__ float s_max, s_sum;
  int tid = threadIdx.x;
  int wid = tid >> 6, lane = tid & 63;
  float a = tens[tid], b = tens[tid + 1024];
  float mx = fmaxf(a, b);
  for (int off = 32; off; off >>= 1) mx = fmaxf(mx, __shfl_down(mx, off));
  if (lane == 0) red[wid] = mx;
  __syncthreads();
  if (tid == 0) {
    float m2 = red[0];
    for (int i = 1; i < 16; ++i) m2 = fmaxf(m2, red[i]);
    s_max = m2;
  }
  __syncthreads();
  float mxv = s_max;
  float ea = expf(a - mxv), eb = expf(b - mxv);
  float se = ea + eb;
  for (int off = 32; off; off >>= 1) se += __shfl_down(se, off);
  __syncthreads();
  if (lane == 0) red[wid] = se;
  __syncthreads();
  if (tid == 0) {
    float s2 = 0.f;
    for (int i = 0; i < 16; ++i) s2 += red[i];
    s_sum = s2;
  }
  __syncthreads();
  float inv = 1.f / s_sum;
  wsoft[tid] = ea * inv;
  wsoft[tid + 1024] = eb * inv;
  float st = a + b;
  for (int off = 32; off; off >>= 1) st += __shfl_down(st, off);
  __syncthreads();
  if (lane == 0) red[wid] = st;
  __syncthreads();
  if (tid == 0) {
    float s2 = 0.f;
    for (int i = 0; i < 16; ++i) s2 += red[i];
    meanT_out[0] = s2 * (1.f / 2048.f);
  }
}

// ---------------- combine stage1 ----------------
__global__ __launch_bounds__(256) void k_comb_part(
    const float* __restrict__ ore, const float* __restrict__ oim,
    const float* __restrict__ wsoft, float* __restrict__ cpart) {
  int j = blockIdx.x * 256 + threadIdx.x;
  int mc = blockIdx.y;
  const float* src = (j < 512) ? ore : oim;
  int col = j & 511;
  float s = 0.f;
  for (int i = 0; i < 128; ++i) {
    int m = mc * 128 + i;
    s += wsoft[m] * src[(size_t)m * D_OUT + col];
  }
  cpart[(size_t)mc * 1024 + j] = s;
}

// ---------------- pred stage1 (comb reduction fused in) ----------------
__global__ __launch_bounds__(256) void k_pred_part(
    const float* __restrict__ cpart, const float* __restrict__ oh_w,
    float* __restrict__ ppart) {
  __shared__ float combs[128];
  int tid = threadIdx.x;
  int jc = blockIdx.y;
  if (tid < 128) {
    float s = 0.f;
#pragma unroll
    for (int mc = 0; mc < 16; ++mc) s += cpart[(size_t)mc * 1024 + jc * 128 + tid];
    combs[tid] = s;
  }
  __syncthreads();
  int n = blockIdx.x * 256 + tid;
  float s = 0.f;
  for (int i = 0; i < 128; ++i)
    s += combs[i] * oh_w[(size_t)(jc * 128 + i) * D_IN + n];
  ppart[(size_t)jc * D_IN + n] = s;
}

__global__ __launch_bounds__(256) void k_pred_red(
    const float* __restrict__ ppart, const float* __restrict__ oh_b,
    float* __restrict__ pred) {
  int n = blockIdx.x * 256 + threadIdx.x;
  float s = oh_b[n];
#pragma unroll
  for (int jc = 0; jc < 8; ++jc) s += ppart[(size_t)jc * D_IN + n];
  pred[n] = s;
}

// ---------------- launcher ----------------
extern "C" void kernel_launch(void* const* d_in, const int* in_sizes, int n_in,
                              void* d_out, int out_size, void* d_ws, size_t ws_size,
                              hipStream_t stream) {
  const float* x     = (const float*)d_in[0];
  const float* h_re  = (const float*)d_in[1];
  const float* h_im  = (const float*)d_in[2];
  const float* ea_wr = (const float*)d_in[3];
  const float* ea_br = (const float*)d_in[4];
  const float* ea_wi = (const float*)d_in[5];
  const float* ea_bi = (const float*)d_in[6];
  const float* eg_wr = (const float*)d_in[7];
  const float* eg_br = (const float*)d_in[8];
  const float* eg_wi = (const float*)d_in[9];
  const float* eg_bi = (const float*)d_in[10];
  const float* gz_w  = (const float*)d_in[11];
  const float* gz_b  = (const float*)d_in[12];
  const float* gr_w  = (const float*)d_in[13];
  const float* gr_b  = (const float*)d_in[14];
  const float* ghr_w = (const float*)d_in[15];
  const float* ghr_b = (const float*)d_in[16];
  const float* ghi_w = (const float*)d_in[17];
  const float* ghi_b = (const float*)d_in[18];
  const float* oh_w  = (const float*)d_in[19];
  const float* oh_b  = (const float*)d_in[20];
  const int*   step  = (const int*)d_in[21];

  float* out = (float*)d_out;
  float* pred_out  = out;
  float* meanT_out = out + 512;
  float* nhre_out  = out + 513;
  float* nhim_out  = out + 513 + N_CELLS * D_HID;

  char* p = (char*)d_ws;
  auto carve = [&](size_t bytes) { char* r = p; p += (bytes + 255) & ~(size_t)255; return r; };
  short* wdrT   = (short*)carve(512 * 1024 * 2);
  short* wdiT   = (short*)carve(512 * 1024 * 2);
  short* wdnT   = (short*)carve(512 * 1024 * 2);
  short* gzwT   = (short*)carve(1024 * 1536 * 2);
  short* grwT   = (short*)carve(1024 * 1536 * 2);
  short* ghrwT  = (short*)carve(1024 * 1536 * 2);
  short* ghiwT  = (short*)carve(1024 * 1536 * 2);
  short* hbre   = (short*)carve(2048 * 1024 * 2);
  short* hbim   = (short*)carve(2048 * 1024 * 2);
  short* gatesA = (short*)carve((size_t)2048 * 1536 * 2);
  short* candAre= (short*)carve((size_t)2048 * 1536 * 2);
  short* candAim= (short*)carve((size_t)2048 * 1536 * 2);
  float* ore    = (float*)carve(2048 * 512 * 4);
  float* oim    = (float*)carve(2048 * 512 * 4);
  unsigned short* zbuf = (unsigned short*)carve((size_t)2048 * 1024 * 2);
  float* bpartr = (float*)carve(8 * 512 * 4);
  float* bparti = (float*)carve(8 * 512 * 4);
  float* tens   = (float*)carve(2048 * 4);
  float* fsbuf  = (float*)carve(2 * 8192 * 4);
  float* wsoft  = (float*)carve(2048 * 4);
  float* cpart  = (float*)carve(16 * 1024 * 4);
  float* ppart  = (float*)carve(8 * 512 * 4);

  hipLaunchKernelGGL(k_prep_all, dim3(8736), dim3(256), 0, stream,
                     gz_w, gr_w, ghr_w, ghi_w, gzwT, grwT, ghrwT, ghiwT,
                     ea_wr, eg_wr, ea_wi, eg_wi, wdrT, wdiT, wdnT,
                     h_re, h_im, hbre, hbim, gatesA, tens,
                     x, bpartr, bparti, fsbuf);
  hipLaunchKernelGGL(k_engine, dim3(32, 16), dim3(256), 0, stream,
                     hbre, hbim, wdrT, wdiT, wdnT,
                     bpartr, bparti, ea_br, ea_bi, eg_br, eg_bi,
                     ore, oim, gatesA, candAre, candAim, tens);
  hipLaunchKernelGGL(k_gates, dim3(32, 16, 2), dim3(256), 0, stream,
                     gatesA, gzwT, grwT, gz_w, gz_b, gr_w, gr_b, tens,
                     h_re, h_im, zbuf, candAre, candAim);
  hipLaunchKernelGGL(k_cand, dim3(32, 16, 2), dim3(256), 0, stream,
                     candAre, candAim, ghrwT, ghiwT, ghr_b, ghi_b, ghr_w,
                     tens, zbuf, h_re, h_im, nhre_out, nhim_out);
  hipLaunchKernelGGL(k_fsum_part, dim3(64, 2), dim3(256), 0, stream,
                     nhre_out, nhim_out, fsbuf);
  hipLaunchKernelGGL(k_sync, dim3((N_CELLS * D_HID) / 256), dim3(256), 0, stream,
                     nhre_out, nhim_out, fsbuf, step);
  hipLaunchKernelGGL(k_stats, dim3(1), dim3(1024), 0, stream, tens, wsoft, meanT_out);
  hipLaunchKernelGGL(k_comb_part, dim3(4, 16), dim3(256), 0, stream,
                     ore, oim, wsoft, cpart);
  hipLaunchKernelGGL(k_pred_part, dim3(2, 8), dim3(256), 0, stream, cpart, oh_w, ppart);
  hipLaunchKernelGGL(k_pred_red, dim3(2), dim3(256), 0, stream, ppart, oh_b, pred_out);
}